// Round 10
// baseline (6549.886 us; speedup 1.0000x reference)
//
#include <hip/hip_runtime.h>

#define D 512
#define C 1024
#define BM 128
#define BN 128
#define NCHUNK 8    // C / BN
#define KSTEPS 16   // D / 32
#define NSTG 8      // D / 64 (staging steps)
#define NBLK_CU 8192

typedef _Float16 f16x8 __attribute__((ext_vector_type(8)));
typedef float f32x4 __attribute__((ext_vector_type(4)));

__device__ __forceinline__ void gll16(const void* g, void* l) {
    __builtin_amdgcn_global_load_lds(
        (const __attribute__((address_space(1))) void*)g,
        (__attribute__((address_space(3))) void*)l, 16, 0, 0);
}

// lexicographic (score, index) insert into sorted top-3 (scalar refs only)
__device__ __forceinline__ void ins3(float s, int i,
                                     float& s1, int& i1, float& s2, int& i2,
                                     float& s3, int& i3) {
    if (s < s1 || (s == s1 && i < i1)) { s3 = s2; i3 = i2; s2 = s1; i2 = i1; s1 = s; i1 = i; }
    else if (s < s2 || (s == s2 && i < i2)) { s3 = s2; i3 = i2; s2 = s; i2 = i; }
    else if (s < s3 || (s == s3 && i < i3)) { s3 = s; i3 = i; }
}

// ---- ||c||^2 for all Q*C codes (fp32)
__global__ __launch_bounds__(256) void cbnorm_kernel(const float* __restrict__ cb,
                                                     float* __restrict__ cbn) {
    int code = blockIdx.x * 4 + (threadIdx.x >> 6);
    int lane = threadIdx.x & 63;
    const float* row = cb + (size_t)code * D;
    float4 a = *(const float4*)(row + lane * 8);
    float4 b = *(const float4*)(row + lane * 8 + 4);
    float s = a.x*a.x + a.y*a.y + a.z*a.z + a.w*a.w
            + b.x*b.x + b.y*b.y + b.z*b.z + b.w*b.w;
    #pragma unroll
    for (int off = 32; off > 0; off >>= 1) s += __shfl_down(s, off, 64);
    if (lane == 0) cbn[code] = s;
}

// ---- f16 plane of codebooks in MFMA-fragment tile order.
// uint4 index t = ((q*8+cc)*16+ks)*512 + tile*64 + ksub*16 + col
__global__ __launch_bounds__(256) void cb_split_kernel(const float* __restrict__ cbs,
                                                       uint4* __restrict__ hi_plane) {
    int t = blockIdx.x * 256 + threadIdx.x;
    int rg = t >> 9;
    int u  = t & 511;
    int q  = rg >> 7;
    int cc = (rg >> 4) & 7;
    int ks = rg & 15;
    int tile = u >> 6;
    int ksub = (u >> 4) & 3;
    int col  = u & 15;
    int code = cc * 128 + tile * 16 + col;
    int d0   = ks * 32 + ksub * 8;
    const float* src = cbs + ((size_t)q * C + code) * D + d0;
    float4 v0 = *(const float4*)src;
    float4 v1 = *(const float4*)(src + 4);
    float xv[8] = {v0.x, v0.y, v0.z, v0.w, v1.x, v1.y, v1.z, v1.w};
    f16x8 h;
    #pragma unroll
    for (int e = 0; e < 8; ++e) h[e] = (_Float16)xv[e];
    hi_plane[t] = __builtin_bit_cast(uint4, h);
}

// ---- 1-pass f16 MFMA distance GEMM, BK=64 double-buffered (64 KiB LDS — this
// size is deliberate: it gates occupancy at 2 blocks/CU, which keeps the
// register allocator from squeezing VGPRs to 52-64 and spilling acc to scratch
// (rounds 6-9: 32KB LDS -> VGPR 52, WRITE_SIZE 600-850MB, 3x slower).
__global__ __launch_bounds__(256, 2) void vq_mfma_step(
    const float* __restrict__ rin,     // fp32 residual (or x at q=0)
    const uint4* __restrict__ bhq,     // f16 plane of this codebook
    const float* __restrict__ cbnq,    // [C] norms
    float4*      __restrict__ partial) // [P][16]: (s1,s2,s3, packed i1|i2<<10|i3<<20)
{
    __shared__ uint4 SH[2][2][1024];   // [buf][0=A,1=B][2 ks-planes x 512] = 64 KiB
    const int tid  = threadIdx.x;
    const int lane = tid & 63;
    const int wv   = tid >> 6;
    const int wm   = wv >> 1, wn = wv & 1;
    const int bm   = blockIdx.x & 255;   // stride-256 cc siblings share XCD/L2
    const int cc   = blockIdx.x >> 8;
    const int bp   = bm * BM;

    f32x4 acc[4][4];
    #pragma unroll
    for (int i = 0; i < 4; ++i)
        #pragma unroll
        for (int j = 0; j < 4; ++j) acc[i][j] = (f32x4){0.f, 0.f, 0.f, 0.f};

    auto STAGE = [&](int buf, int kst) {   // kst: 0..7, covers k = kst*64 .. +64
        const uint4* bh = bhq + (size_t)(cc * KSTEPS + kst * 2) * 512;
        gll16(bh + tid,       &SH[buf][1][tid]);
        gll16(bh + tid + 256, &SH[buf][1][tid + 256]);
        gll16(bh + tid + 512, &SH[buf][1][tid + 512]);
        gll16(bh + tid + 768, &SH[buf][1][tid + 768]);
        #pragma unroll
        for (int it = 0; it < 4; ++it) {
            int oct  = tid + it * 256;          // ksl*512 + tile*64 + ksub*16 + col
            int rem  = oct & 511;
            int row  = ((rem >> 6) << 4) + (rem & 15);
            int ksub = (rem >> 4) & 3;
            const float* src = rin + (size_t)(bp + row) * D
                             + kst * 64 + (oct >> 9) * 32 + ksub * 8;
            float4 v0 = *(const float4*)src;
            float4 v1 = *(const float4*)(src + 4);
            float xv[8] = {v0.x, v0.y, v0.z, v0.w, v1.x, v1.y, v1.z, v1.w};
            f16x8 h;
            #pragma unroll
            for (int e = 0; e < 8; ++e) h[e] = (_Float16)xv[e];
            SH[buf][0][oct] = __builtin_bit_cast(uint4, h);
        }
    };

    STAGE(0, 0);
    int buf = 0;
    for (int kst = 0; kst < NSTG; ++kst) {
        __syncthreads();
        if (kst + 1 < NSTG) STAGE(buf ^ 1, kst + 1);
        #pragma unroll
        for (int ksl = 0; ksl < 2; ++ksl) {
            f16x8 ah[4], bh[4];
            #pragma unroll
            for (int mt = 0; mt < 4; ++mt)
                ah[mt] = __builtin_bit_cast(f16x8, SH[buf][0][ksl * 512 + (wm * 4 + mt) * 64 + lane]);
            #pragma unroll
            for (int nt = 0; nt < 4; ++nt)
                bh[nt] = __builtin_bit_cast(f16x8, SH[buf][1][ksl * 512 + (wn * 4 + nt) * 64 + lane]);
            #pragma unroll
            for (int mt = 0; mt < 4; ++mt)
                #pragma unroll
                for (int nt = 0; nt < 4; ++nt)
                    acc[mt][nt] = __builtin_amdgcn_mfma_f32_16x16x32_f16(ah[mt], bh[nt], acc[mt][nt], 0, 0, 0);
        }
        buf ^= 1;
    }

    // epilogue: score = ||c||^2 - 2 r.c ; per-wave top-3 over its 64 codes
    const int colbase = cc * BN;
    float cbn_l[4];
    int   ci_l[4];
    #pragma unroll
    for (int nt = 0; nt < 4; ++nt) {
        ci_l[nt]  = colbase + (wn * 4 + nt) * 16 + (lane & 15);
        cbn_l[nt] = cbnq[ci_l[nt]];
    }
    #pragma unroll
    for (int mt = 0; mt < 4; ++mt) {
        #pragma unroll
        for (int r = 0; r < 4; ++r) {
            float s1 = 3.4e38f, s2 = 3.4e38f, s3 = 3.4e38f;
            int i1 = 1023, i2 = 1023, i3 = 1023;
            #pragma unroll
            for (int nt = 0; nt < 4; ++nt) {
                float s = fmaf(-2.f, acc[mt][nt][r], cbn_l[nt]);
                ins3(s, ci_l[nt], s1, i1, s2, i2, s3, i3);
            }
            #pragma unroll
            for (int m = 1; m < 16; m <<= 1) {
                float o1 = __shfl_xor(s1, m, 64); int oi1 = __shfl_xor(i1, m, 64);
                float o2 = __shfl_xor(s2, m, 64); int oi2 = __shfl_xor(i2, m, 64);
                float o3 = __shfl_xor(s3, m, 64); int oi3 = __shfl_xor(i3, m, 64);
                ins3(o1, oi1, s1, i1, s2, i2, s3, i3);
                ins3(o2, oi2, s1, i1, s2, i2, s3, i3);
                ins3(o3, oi3, s1, i1, s2, i2, s3, i3);
            }
            if ((lane & 15) == 0) {
                int row = bp + wm * 64 + mt * 16 + (lane >> 4) * 4 + r;
                unsigned pk = (unsigned)i1 | ((unsigned)i2 << 10) | ((unsigned)i3 << 20);
                partial[(size_t)row * 16 + cc * 2 + wn] =
                    make_float4(s1, s2, s3, __builtin_bit_cast(float, pk));
            }
        }
    }
}

// ---- merge 16 top-3s -> global top-3; fp64 rescore all 3 (exact argmin);
//      residual update + per-block loss partial. No atomics.
__global__ __launch_bounds__(256) void combine_update(
    const float* __restrict__ rin, float* __restrict__ rout,
    const float* __restrict__ cbq,
    const float4* __restrict__ partial,
    float* __restrict__ idx_out, float* __restrict__ blockloss,
    int q, int nq)
{
    __shared__ float wls[4];
    const int lane = threadIdx.x & 63;
    const int wv   = threadIdx.x >> 6;
    const int p    = blockIdx.x * 4 + wv;

    float s1 = 3.4e38f, s2 = 3.4e38f, s3 = 3.4e38f;
    int i1 = 1023, i2 = 1023, i3 = 1023;
    if (lane < 16) {
        float4 v = partial[(size_t)p * 16 + lane];
        unsigned pk = __builtin_bit_cast(unsigned, v.w);
        s1 = v.x; s2 = v.y; s3 = v.z;
        i1 = pk & 1023; i2 = (pk >> 10) & 1023; i3 = (pk >> 20) & 1023;
    }
    #pragma unroll
    for (int m = 1; m < 16; m <<= 1) {
        float o1 = __shfl_xor(s1, m, 64); int oi1 = __shfl_xor(i1, m, 64);
        float o2 = __shfl_xor(s2, m, 64); int oi2 = __shfl_xor(i2, m, 64);
        float o3 = __shfl_xor(s3, m, 64); int oi3 = __shfl_xor(i3, m, 64);
        ins3(o1, oi1, s1, i1, s2, i2, s3, i3);
        ins3(o2, oi2, s1, i1, s2, i2, s3, i3);
        ins3(o3, oi3, s1, i1, s2, i2, s3, i3);
    }
    i1 = __shfl(i1, 0, 64);
    i2 = __shfl(i2, 0, 64);
    i3 = __shfl(i3, 0, 64);

    const float* rrow = rin + (size_t)p * D;
    float4 r0 = *(const float4*)(rrow + lane * 8);
    float4 r1 = *(const float4*)(rrow + lane * 8 + 4);
    const float* c1 = cbq + (size_t)i1 * D;
    const float* c2 = cbq + (size_t)i2 * D;
    const float* c3 = cbq + (size_t)i3 * D;
    float4 a0 = *(const float4*)(c1 + lane * 8), a1 = *(const float4*)(c1 + lane * 8 + 4);
    float4 b0 = *(const float4*)(c2 + lane * 8), b1 = *(const float4*)(c2 + lane * 8 + 4);
    float4 g0 = *(const float4*)(c3 + lane * 8), g1 = *(const float4*)(c3 + lane * 8 + 4);
    float ra[8] = {r0.x, r0.y, r0.z, r0.w, r1.x, r1.y, r1.z, r1.w};
    float aa[8] = {a0.x, a0.y, a0.z, a0.w, a1.x, a1.y, a1.z, a1.w};
    float bb[8] = {b0.x, b0.y, b0.z, b0.w, b1.x, b1.y, b1.z, b1.w};
    float gg[8] = {g0.x, g0.y, g0.z, g0.w, g1.x, g1.y, g1.z, g1.w};

    double d1 = 0.0, d2 = 0.0, d3 = 0.0;
    #pragma unroll
    for (int e = 0; e < 8; ++e) {
        double rr = (double)ra[e];
        double av = (double)aa[e], bv = (double)bb[e], gv = (double)gg[e];
        d1 += av * av - 2.0 * rr * av;
        d2 += bv * bv - 2.0 * rr * bv;
        d3 += gv * gv - 2.0 * rr * gv;
    }
    #pragma unroll
    for (int m = 32; m > 0; m >>= 1) {
        d1 += __shfl_xor(d1, m, 64);
        d2 += __shfl_xor(d2, m, 64);
        d3 += __shfl_xor(d3, m, 64);
    }
    int    fi = i1;
    double fd = d1;
    if (d2 < fd || (d2 == fd && i2 < fi)) { fd = d2; fi = i2; }
    if (d3 < fd || (d3 == fd && i3 < fi)) { fd = d3; fi = i3; }
    if (lane == 0) idx_out[(size_t)p * nq + q] = (float)fi;

    float nsum = 0.f;
    float nv[8];
    #pragma unroll
    for (int e = 0; e < 8; ++e) {
        float cv = (fi == i1) ? aa[e] : ((fi == i2) ? bb[e] : gg[e]);
        nv[e] = ra[e] - cv;
        nsum = fmaf(nv[e], nv[e], nsum);
    }
    float4 w0 = {nv[0], nv[1], nv[2], nv[3]};
    float4 w1 = {nv[4], nv[5], nv[6], nv[7]};
    *(float4*)(rout + (size_t)p * D + lane * 8)     = w0;
    *(float4*)(rout + (size_t)p * D + lane * 8 + 4) = w1;
    #pragma unroll
    for (int off = 32; off > 0; off >>= 1) nsum += __shfl_down(nsum, off, 64);
    if (lane == 0) wls[wv] = nsum;
    __syncthreads();
    if (threadIdx.x == 0)
        blockloss[(size_t)q * NBLK_CU + blockIdx.x] = wls[0] + wls[1] + wls[2] + wls[3];
}

// ---- quantized = x - final_residual (in place); blocks 0..nq-1 reduce losses.
__global__ __launch_bounds__(256) void finalize_kernel(
    const float* __restrict__ x, float* __restrict__ outq,
    const float* __restrict__ blockloss,
    float* __restrict__ losses, float invPD, int n4, int nq)
{
    if (blockIdx.x < (unsigned)nq) {
        __shared__ float wls[4];
        int q = blockIdx.x;
        float s = 0.f;
        for (int i = threadIdx.x; i < NBLK_CU; i += 256)
            s += blockloss[(size_t)q * NBLK_CU + i];
        #pragma unroll
        for (int off = 32; off > 0; off >>= 1) s += __shfl_down(s, off, 64);
        if ((threadIdx.x & 63) == 0) wls[threadIdx.x >> 6] = s;
        __syncthreads();
        if (threadIdx.x == 0) {
            float vq = (wls[0] + wls[1] + wls[2] + wls[3]) * invPD;
            losses[q] = vq;
            losses[nq + q] = 0.25f * vq;
        }
    }
    int stride = gridDim.x * blockDim.x;
    for (int i = blockIdx.x * blockDim.x + threadIdx.x; i < n4; i += stride) {
        float4 xv = ((const float4*)x)[i];
        float4 rv = ((float4*)outq)[i];
        float4 qv;
        qv.x = xv.x - rv.x;
        qv.y = xv.y - rv.y;
        qv.z = xv.z - rv.z;
        qv.w = xv.w - rv.w;
        ((float4*)outq)[i] = qv;
    }
}

extern "C" void kernel_launch(void* const* d_in, const int* in_sizes, int n_in,
                              void* d_out, int out_size, void* d_ws, size_t ws_size,
                              hipStream_t stream)
{
    const float* x   = (const float*)d_in[0];
    const float* cbs = (const float*)d_in[1];
    const int PD = in_sizes[0];                // 16777216
    const int P  = PD / D;                     // 32768
    const int nq = in_sizes[1] / (C * D);      // 8

    float* out     = (float*)d_out;
    float* resid   = out;
    float* idx_out = out + (size_t)PD;
    float* losses  = idx_out + (size_t)P * nq;

    // ws: [0,8M) cb f16 planes | +32KB cbn | partial 8M | blockloss 256K (~17 MB)
    char* wsb = (char*)d_ws;
    uint4*  cb_hi     = (uint4*)wsb;
    float*  cbn       = (float*)(wsb + 8388608);
    float4* partial   = (float4*)(wsb + 8421376);
    float*  blockloss = (float*)(wsb + 16809984);

    cbnorm_kernel<<<nq * C / 4, 256, 0, stream>>>(cbs, cbn);
    cb_split_kernel<<<nq * C * D / 8 / 256, 256, 0, stream>>>(cbs, cb_hi);

    for (int q = 0; q < nq; ++q) {
        const float* rin = (q == 0) ? x : resid;
        vq_mfma_step<<<(P / BM) * NCHUNK, 256, 0, stream>>>(
            rin, cb_hi + (size_t)q * 65536, cbn + (size_t)q * C, partial);
        combine_update<<<P / 4, 256, 0, stream>>>(
            rin, resid, cbs + (size_t)q * C * D, partial,
            idx_out, blockloss, q, nq);
    }
    finalize_kernel<<<2048, 256, 0, stream>>>(x, out, blockloss, losses,
                                              1.f / (float)PD, PD / 4, nq);
}

// Round 11
// 1662.418 us; speedup vs baseline: 3.9400x; 3.9400x over previous
//
#include <hip/hip_runtime.h>

#define D 512
#define C 1024
#define BM 128
#define BN 128
#define BK 32
#define NCHUNK 8    // C / BN
#define KSTEPS 16   // D / BK
#define NBLK_CU 8192  // combine_update blocks (P/4)

typedef _Float16 f16x8 __attribute__((ext_vector_type(8)));
typedef float f32x4 __attribute__((ext_vector_type(4)));

__device__ __forceinline__ void gll16(const void* g, void* l) {
    __builtin_amdgcn_global_load_lds(
        (const __attribute__((address_space(1))) void*)g,
        (__attribute__((address_space(3))) void*)l, 16, 0, 0);
}

// ---- ||c||^2 for all Q*C codes (fp32)
__global__ __launch_bounds__(256) void cbnorm_kernel(const float* __restrict__ cb,
                                                     float* __restrict__ cbn) {
    int code = blockIdx.x * 4 + (threadIdx.x >> 6);
    int lane = threadIdx.x & 63;
    const float* row = cb + (size_t)code * D;
    float4 a = *(const float4*)(row + lane * 8);
    float4 b = *(const float4*)(row + lane * 8 + 4);
    float s = a.x*a.x + a.y*a.y + a.z*a.z + a.w*a.w
            + b.x*b.x + b.y*b.y + b.z*b.z + b.w*b.w;
    #pragma unroll
    for (int off = 32; off > 0; off >>= 1) s += __shfl_down(s, off, 64);
    if (lane == 0) cbn[code] = s;
}

// ---- split fp32 codebooks into f16 hi/lo planes, stored in MFMA-fragment tile order.
__global__ __launch_bounds__(256) void cb_split_kernel(const float* __restrict__ cbs,
                                                       uint4* __restrict__ hi_plane,
                                                       uint4* __restrict__ lo_plane) {
    int t = blockIdx.x * 256 + threadIdx.x;
    int rg = t >> 9;
    int u  = t & 511;
    int q  = rg >> 7;
    int cc = (rg >> 4) & 7;
    int ks = rg & 15;
    int ctile = u >> 6;
    int ksub  = (u >> 4) & 3;
    int col   = u & 15;
    int code  = cc * 128 + ctile * 16 + col;
    int d0    = ks * 32 + ksub * 8;
    const float* src = cbs + ((size_t)q * C + code) * D + d0;
    float4 v0 = *(const float4*)src;
    float4 v1 = *(const float4*)(src + 4);
    float xv[8] = {v0.x, v0.y, v0.z, v0.w, v1.x, v1.y, v1.z, v1.w};
    f16x8 h, l;
    #pragma unroll
    for (int e = 0; e < 8; ++e) {
        _Float16 hh = (_Float16)xv[e];
        h[e] = hh;
        l[e] = (_Float16)(xv[e] - (float)hh);
    }
    hi_plane[t] = __builtin_bit_cast(uint4, h);
    lo_plane[t] = __builtin_bit_cast(uint4, l);
}

// ---- MFMA distance GEMM, fused top-2 epilogue (per-wave slot, no races).
__global__ __launch_bounds__(256, 2) void vq_mfma_step(
    const float* __restrict__ rin,
    const uint4* __restrict__ bhq,
    const uint4* __restrict__ blq,
    const float* __restrict__ cbnq,
    float4*      __restrict__ partial)  // [P][16]; slot = cc*2 + wn
{
    __shared__ uint4 SH[2][4][512];
    const int tid  = threadIdx.x;
    const int lane = tid & 63;
    const int wv   = tid >> 6;
    const int wm   = wv >> 1, wn = wv & 1;
    const int bm   = blockIdx.x & 255;
    const int cc   = blockIdx.x >> 8;
    const int bp   = bm * BM;

    f32x4 acc[4][4];
    #pragma unroll
    for (int i = 0; i < 4; ++i)
        #pragma unroll
        for (int j = 0; j < 4; ++j) acc[i][j] = (f32x4){0.f, 0.f, 0.f, 0.f};

    auto STAGE = [&](int buf, int ks) {
        const uint4* bh = bhq + (size_t)(cc * KSTEPS + ks) * 512;
        const uint4* bl = blq + (size_t)(cc * KSTEPS + ks) * 512;
        gll16(bh + tid,       &SH[buf][2][tid]);
        gll16(bh + tid + 256, &SH[buf][2][tid + 256]);
        gll16(bl + tid,       &SH[buf][3][tid]);
        gll16(bl + tid + 256, &SH[buf][3][tid + 256]);
        #pragma unroll
        for (int it = 0; it < 2; ++it) {
            int oct  = tid + it * 256;
            int row  = ((oct >> 6) << 4) + (oct & 15);
            int ksub = (oct >> 4) & 3;
            const float* src = rin + (size_t)(bp + row) * D + ks * BK + ksub * 8;
            float4 v0 = *(const float4*)src;
            float4 v1 = *(const float4*)(src + 4);
            float xv[8] = {v0.x, v0.y, v0.z, v0.w, v1.x, v1.y, v1.z, v1.w};
            f16x8 h, l;
            #pragma unroll
            for (int e = 0; e < 8; ++e) {
                _Float16 hh = (_Float16)xv[e];
                h[e] = hh;
                l[e] = (_Float16)(xv[e] - (float)hh);
            }
            SH[buf][0][oct] = __builtin_bit_cast(uint4, h);
            SH[buf][1][oct] = __builtin_bit_cast(uint4, l);
        }
    };

    STAGE(0, 0);
    int buf = 0;
    for (int ks = 0; ks < KSTEPS; ++ks) {
        __syncthreads();
        if (ks + 1 < KSTEPS) STAGE(buf ^ 1, ks + 1);
        f16x8 ah[4], al[4], bh[4], bl[4];
        #pragma unroll
        for (int mt = 0; mt < 4; ++mt) {
            ah[mt] = __builtin_bit_cast(f16x8, SH[buf][0][(wm * 4 + mt) * 64 + lane]);
            al[mt] = __builtin_bit_cast(f16x8, SH[buf][1][(wm * 4 + mt) * 64 + lane]);
        }
        #pragma unroll
        for (int nt = 0; nt < 4; ++nt) {
            bh[nt] = __builtin_bit_cast(f16x8, SH[buf][2][(wn * 4 + nt) * 64 + lane]);
            bl[nt] = __builtin_bit_cast(f16x8, SH[buf][3][(wn * 4 + nt) * 64 + lane]);
        }
        #pragma unroll
        for (int mt = 0; mt < 4; ++mt)
            #pragma unroll
            for (int nt = 0; nt < 4; ++nt) {
                acc[mt][nt] = __builtin_amdgcn_mfma_f32_16x16x32_f16(ah[mt], bh[nt], acc[mt][nt], 0, 0, 0);
                acc[mt][nt] = __builtin_amdgcn_mfma_f32_16x16x32_f16(ah[mt], bl[nt], acc[mt][nt], 0, 0, 0);
                acc[mt][nt] = __builtin_amdgcn_mfma_f32_16x16x32_f16(al[mt], bh[nt], acc[mt][nt], 0, 0, 0);
            }
        buf ^= 1;
    }

    const int colbase = cc * BN;
    float cbn_l[4];
    int   ci_l[4];
    #pragma unroll
    for (int nt = 0; nt < 4; ++nt) {
        ci_l[nt]  = colbase + (wn * 4 + nt) * 16 + (lane & 15);
        cbn_l[nt] = cbnq[ci_l[nt]];
    }
    #pragma unroll
    for (int mt = 0; mt < 4; ++mt) {
        #pragma unroll
        for (int r = 0; r < 4; ++r) {
            float s1 = 3.4e38f, s2 = 3.4e38f;
            int i1 = 1 << 30, i2 = 1 << 30;
            #pragma unroll
            for (int nt = 0; nt < 4; ++nt) {
                float s = fmaf(-2.f, acc[mt][nt][r], cbn_l[nt]);
                int ci = ci_l[nt];
                if (s < s1 || (s == s1 && ci < i1)) { s2 = s1; i2 = i1; s1 = s; i1 = ci; }
                else if (s < s2 || (s == s2 && ci < i2)) { s2 = s; i2 = ci; }
            }
            #pragma unroll
            for (int m = 1; m < 16; m <<= 1) {
                float o1 = __shfl_xor(s1, m, 64); int oi1 = __shfl_xor(i1, m, 64);
                float o2 = __shfl_xor(s2, m, 64); int oi2 = __shfl_xor(i2, m, 64);
                if (o1 < s1 || (o1 == s1 && oi1 < i1)) {
                    if (s1 < o2 || (s1 == o2 && i1 < oi2)) { s2 = s1; i2 = i1; }
                    else { s2 = o2; i2 = oi2; }
                    s1 = o1; i1 = oi1;
                } else {
                    if (o1 < s2 || (o1 == s2 && oi1 < i2)) { s2 = o1; i2 = oi1; }
                }
            }
            if ((lane & 15) == 0) {
                int row = bp + wm * 64 + mt * 16 + (lane >> 4) * 4 + r;
                partial[(size_t)row * 16 + cc * 2 + wn] = make_float4(s1, (float)i1, s2, (float)i2);
            }
        }
    }
}

// ---- merge 16 partial top-2s; fp64-rescore ONLY on near-ties; update residual;
//      per-block loss partial (NO same-address atomics).
__global__ __launch_bounds__(256) void combine_update(
    const float* __restrict__ rin, float* __restrict__ rout,
    const float* __restrict__ cbq,
    const float4* __restrict__ partial,
    float* __restrict__ idx_out, float* __restrict__ blockloss,
    int q, int nq)
{
    __shared__ float wls[4];
    const int lane = threadIdx.x & 63;
    const int wv   = threadIdx.x >> 6;
    const int p    = blockIdx.x * 4 + wv;

    float s1 = 3.4e38f, s2 = 3.4e38f;
    int i1 = 1 << 30, i2 = 1 << 30;
    if (lane < 16) {
        float4 v = partial[(size_t)p * 16 + lane];
        s1 = v.x; i1 = (int)v.y; s2 = v.z; i2 = (int)v.w;
    }
    #pragma unroll
    for (int m = 1; m < 16; m <<= 1) {
        float o1 = __shfl_xor(s1, m, 64); int oi1 = __shfl_xor(i1, m, 64);
        float o2 = __shfl_xor(s2, m, 64); int oi2 = __shfl_xor(i2, m, 64);
        if (o1 < s1 || (o1 == s1 && oi1 < i1)) {
            if (s1 < o2 || (s1 == o2 && i1 < oi2)) { s2 = s1; i2 = i1; }
            else { s2 = o2; i2 = oi2; }
            s1 = o1; i1 = oi1;
        } else {
            if (o1 < s2 || (o1 == s2 && oi1 < i2)) { s2 = o1; i2 = oi1; }
        }
    }
    float s1b = __shfl(s1, 0, 64);
    float s2b = __shfl(s2, 0, 64);
    i1 = __shfl(i1, 0, 64);
    i2 = __shfl(i2, 0, 64);

    const float* rrow = rin + (size_t)p * D;
    const float* c1   = cbq + (size_t)i1 * D;
    float4 r0 = *(const float4*)(rrow + lane * 8);
    float4 r1 = *(const float4*)(rrow + lane * 8 + 4);
    float4 a0 = *(const float4*)(c1 + lane * 8);
    float4 a1 = *(const float4*)(c1 + lane * 8 + 4);
    float ra[8] = {r0.x, r0.y, r0.z, r0.w, r1.x, r1.y, r1.z, r1.w};
    float aa[8] = {a0.x, a0.y, a0.z, a0.w, a1.x, a1.y, a1.z, a1.w};

    int f = i1;
    bool use2 = false;
    if (s2b - s1b <= 0.05f) {   // wave-uniform near-tie: exact fp64 rescore of both
        const float* c2 = cbq + (size_t)i2 * D;
        float4 b0 = *(const float4*)(c2 + lane * 8);
        float4 b1 = *(const float4*)(c2 + lane * 8 + 4);
        float bb[8] = {b0.x, b0.y, b0.z, b0.w, b1.x, b1.y, b1.z, b1.w};
        double da = 0.0, db = 0.0;
        #pragma unroll
        for (int e = 0; e < 8; ++e) {
            double rr = (double)ra[e], av = (double)aa[e], bv = (double)bb[e];
            da += av * av - 2.0 * rr * av;
            db += bv * bv - 2.0 * rr * bv;
        }
        #pragma unroll
        for (int m = 32; m > 0; m >>= 1) {
            da += __shfl_xor(da, m, 64);
            db += __shfl_xor(db, m, 64);
        }
        if (db < da || (db == da && i2 < i1)) { f = i2; use2 = true; }
        if (use2) {
            #pragma unroll
            for (int e = 0; e < 8; ++e) aa[e] = bb[e];
        }
    }
    if (lane == 0) idx_out[(size_t)p * nq + q] = (float)f;

    float nsum = 0.f;
    float nv[8];
    #pragma unroll
    for (int e = 0; e < 8; ++e) {
        nv[e] = ra[e] - aa[e];
        nsum = fmaf(nv[e], nv[e], nsum);
    }
    float4 w0 = {nv[0], nv[1], nv[2], nv[3]};
    float4 w1 = {nv[4], nv[5], nv[6], nv[7]};
    *(float4*)(rout + (size_t)p * D + lane * 8)     = w0;
    *(float4*)(rout + (size_t)p * D + lane * 8 + 4) = w1;
    #pragma unroll
    for (int off = 32; off > 0; off >>= 1) nsum += __shfl_down(nsum, off, 64);
    if (lane == 0) wls[wv] = nsum;
    __syncthreads();
    if (threadIdx.x == 0)
        blockloss[(size_t)q * NBLK_CU + blockIdx.x] = wls[0] + wls[1] + wls[2] + wls[3];
}

// ---- quantized = x - final_residual (in place); blocks 0..nq-1 also reduce losses.
__global__ __launch_bounds__(256) void finalize_kernel(
    const float* __restrict__ x, float* __restrict__ outq,
    const float* __restrict__ blockloss,
    float* __restrict__ losses, float invPD, int n4, int nq)
{
    if (blockIdx.x < (unsigned)nq) {
        __shared__ float wls[4];
        int q = blockIdx.x;
        float s = 0.f;
        for (int i = threadIdx.x; i < NBLK_CU; i += 256)
            s += blockloss[(size_t)q * NBLK_CU + i];
        #pragma unroll
        for (int off = 32; off > 0; off >>= 1) s += __shfl_down(s, off, 64);
        if ((threadIdx.x & 63) == 0) wls[threadIdx.x >> 6] = s;
        __syncthreads();
        if (threadIdx.x == 0) {
            float vq = (wls[0] + wls[1] + wls[2] + wls[3]) * invPD;
            losses[q] = vq;
            losses[nq + q] = 0.25f * vq;
        }
    }
    int stride = gridDim.x * blockDim.x;
    for (int i = blockIdx.x * blockDim.x + threadIdx.x; i < n4; i += stride) {
        float4 xv = ((const float4*)x)[i];
        float4 rv = ((float4*)outq)[i];
        float4 qv;
        qv.x = xv.x - rv.x;
        qv.y = xv.y - rv.y;
        qv.z = xv.z - rv.z;
        qv.w = xv.w - rv.w;
        ((float4*)outq)[i] = qv;
    }
}

extern "C" void kernel_launch(void* const* d_in, const int* in_sizes, int n_in,
                              void* d_out, int out_size, void* d_ws, size_t ws_size,
                              hipStream_t stream)
{
    const float* x   = (const float*)d_in[0];
    const float* cbs = (const float*)d_in[1];
    const int PD = in_sizes[0];
    const int P  = PD / D;
    const int nq = in_sizes[1] / (C * D);

    float* out     = (float*)d_out;
    float* resid   = out;
    float* idx_out = out + (size_t)PD;
    float* losses  = idx_out + (size_t)P * nq;

    // ws: [0,8M) cb_hi | [8M,16M) cb_lo | +32KB cbn | +8M partial | +256KB blockloss
    char* wsb = (char*)d_ws;
    uint4*  cb_hi     = (uint4*)wsb;
    uint4*  cb_lo     = (uint4*)(wsb + 8388608);
    float*  cbn       = (float*)(wsb + 16777216);
    float4* partial   = (float4*)(wsb + 16809984);
    float*  blockloss = (float*)(wsb + 25198592);

    cbnorm_kernel<<<nq * C / 4, 256, 0, stream>>>(cbs, cbn);
    cb_split_kernel<<<nq * C * D / 8 / 256, 256, 0, stream>>>(cbs, cb_hi, cb_lo);

    for (int q = 0; q < nq; ++q) {
        vq_mfma_step<<<(P / BM) * NCHUNK, 256, 0, stream>>>(
            q == 0 ? x : resid,
            cb_hi + (size_t)q * 65536, cb_lo + (size_t)q * 65536,
            cbn + (size_t)q * C, partial);
        combine_update<<<P / 4, 256, 0, stream>>>(
            q == 0 ? x : resid, resid,
            cbs + (size_t)q * C * D, partial,
            idx_out, blockloss, q, nq);
    }
    finalize_kernel<<<2048, 256, 0, stream>>>(x, out, blockloss, losses,
                                              1.f / (float)PD, PD / 4, nq);
}